// Round 1
// baseline (210.508 us; speedup 1.0000x reference)
//
#include <hip/hip_runtime.h>
#include <stdint.h>

// 3x3 conv, stride 1, pad 1, NCHW fp32 -> implicit GEMM on bf16 MFMA.
// M = OC = 128, N = pixels = 16*112*112 = 200704, K = 9*64 = 576 (k = tap*64 + ic).
// C tile per block: 128 oc x 128 pixels; 12544 % 128 == 0 so a tile never crosses images.

#define HW     112
#define PIX    12544      // 112*112
#define ICN    64
#define OCN    128
#define KDIM   576        // 9*64
#define TILEP  128
#define PTILES 98         // 12544/128
#define NBLK   1568       // 16*98
#define LDS_LD 40         // padded row (bf16 elems): 80B rows -> conflict-free b128 access

typedef __attribute__((ext_vector_type(8))) __bf16 bf16x8;
typedef __attribute__((ext_vector_type(4))) float  f32x4;

__device__ __forceinline__ uint32_t rne_bf16(uint32_t u) {
    return (u + 0x7fffu + ((u >> 16) & 1u)) >> 16;
}

// Transpose+convert weights: Wt[oc][r*64+ic] (bf16) = w[oc][ic][ky][kx] with r=ky*3+kx.
__global__ void prep_weights(const float* __restrict__ w, uint16_t* __restrict__ wt) {
    int idx = blockIdx.x * 256 + threadIdx.x;        // 73728 = 288*256 exactly
    int oc  = idx / KDIM;
    int rem = idx - oc * KDIM;                        // r*64 + ic
    int r   = rem >> 6;
    int ic  = rem & 63;
    uint32_t u = __builtin_bit_cast(uint32_t, w[oc * KDIM + ic * 9 + r]);
    wt[idx] = (uint16_t)rne_bf16(u);
}

__global__ void __launch_bounds__(256)
conv_mfma(const float* __restrict__ x, const uint16_t* __restrict__ wt,
          const float* __restrict__ bias, float* __restrict__ out) {
    __shared__ uint16_t As[OCN * LDS_LD];    // weights [oc][k'] k-contiguous, padded
    __shared__ uint16_t Xs[TILEP * LDS_LD];  // im2col  [pix][k'] k-contiguous, padded

    const int t = threadIdx.x;
    const int b = blockIdx.x;
    const int n_img = b / PTILES;
    const int p0 = (b - n_img * PTILES) * TILEP;

    // ---- x staging coords (fixed per thread): pixel sm, ic-subchunk shalf
    const int sm    = t & 127;
    const int shalf = t >> 7;                // 0/1 -> 16-ic half
    const int sp = p0 + sm;
    const int sh = sp / HW;
    const int sw = sp - sh * HW;
    const float* xn = x + (size_t)n_img * (ICN * PIX);

    // ---- weight staging coords: 2 threads per oc row, 2x16B chunks each
    const int woc = t >> 1;
    const int wch = (t & 1) * 2;

    // ---- compute mapping: 4 waves in 2x2 over the 128x128 tile
    const int lane = t & 63;
    const int wave = t >> 6;
    const int lr = lane & 15;
    const int lq = lane >> 4;
    const int oc_base = (wave & 1) * 64;     // M (oc) offset for this wave
    const int px_base = (wave >> 1) * 64;    // N (pixel) offset for this wave

    f32x4 acc[4][4];
    {
        f32x4 z = {0.f, 0.f, 0.f, 0.f};
#pragma unroll
        for (int i = 0; i < 4; ++i)
#pragma unroll
            for (int j = 0; j < 4; ++j) acc[i][j] = z;
    }

    for (int kb = 0; kb < 18; ++kb) {
        const int r  = kb >> 1;              // tap 0..8
        const int dy = (r / 3) - 1;
        const int dx = (r - (r / 3) * 3) - 1;

        // ---- global loads for this K-step (before barrier)
        uint4 wv0, wv1;
        {
            const uint4* gsrc = (const uint4*)(wt + (size_t)woc * KDIM + kb * 32);
            wv0 = gsrc[wch];
            wv1 = gsrc[wch + 1];
        }
        const int hh = sh + dy;
        const int ww = sw + dx;
        const bool valid = ((unsigned)hh < HW) & ((unsigned)ww < HW);
        const float* xsrc = xn + (size_t)((kb & 1) * 32 + shalf * 16) * PIX + hh * HW + ww;
        uint32_t pk[8];
#pragma unroll
        for (int j = 0; j < 8; ++j) {
            float f0 = valid ? xsrc[(2 * j) * PIX] : 0.0f;
            float f1 = valid ? xsrc[(2 * j + 1) * PIX] : 0.0f;
            uint32_t u0 = rne_bf16(__builtin_bit_cast(uint32_t, f0));
            uint32_t u1 = __builtin_bit_cast(uint32_t, f1);
            u1 = (u1 + 0x7fffu + ((u1 >> 16) & 1u)) & 0xffff0000u;
            pk[j] = u0 | u1;                 // lo = element 2j, hi = element 2j+1
        }

        __syncthreads();                      // previous iteration done reading LDS
        // weights -> As[oc][k']
        {
            char* wdst = (char*)As + woc * (LDS_LD * 2);
            *(uint4*)(wdst + wch * 16)       = wv0;
            *(uint4*)(wdst + (wch + 1) * 16) = wv1;
        }
        // im2col -> Xs[pix][k']  (k' = shalf*16 + e, contiguous)
        {
            char* xdst = (char*)Xs + sm * (LDS_LD * 2) + shalf * 32;
            *(uint4*)(xdst)      = make_uint4(pk[0], pk[1], pk[2], pk[3]);
            *(uint4*)(xdst + 16) = make_uint4(pk[4], pk[5], pk[6], pk[7]);
        }
        __syncthreads();

        // ---- fragments: A lane&15 -> oc, quad*8+j -> k ; B lane&15 -> pixel
        bf16x8 a_frag[4], b_frag[4];
#pragma unroll
        for (int mi = 0; mi < 4; ++mi)
            a_frag[mi] = *(const bf16x8*)((const char*)As +
                          (oc_base + mi * 16 + lr) * (LDS_LD * 2) + lq * 16);
#pragma unroll
        for (int ni = 0; ni < 4; ++ni)
            b_frag[ni] = *(const bf16x8*)((const char*)Xs +
                          (px_base + ni * 16 + lr) * (LDS_LD * 2) + lq * 16);

#pragma unroll
        for (int mi = 0; mi < 4; ++mi)
#pragma unroll
            for (int ni = 0; ni < 4; ++ni)
                acc[mi][ni] = __builtin_amdgcn_mfma_f32_16x16x32_bf16(
                    a_frag[mi], b_frag[ni], acc[mi][ni], 0, 0, 0);
    }

    // ---- epilogue: D row = quad*4 + reg -> oc ; col = lane&15 -> pixel (contiguous)
#pragma unroll
    for (int mi = 0; mi < 4; ++mi) {
#pragma unroll
        for (int rg = 0; rg < 4; ++rg) {
            const int oc = oc_base + mi * 16 + lq * 4 + rg;
            const float bb = bias[oc];
            float* orow = out + ((size_t)n_img * OCN + oc) * PIX + p0 + px_base + lr;
#pragma unroll
            for (int ni = 0; ni < 4; ++ni)
                orow[ni * 16] = acc[mi][ni][rg] + bb;
        }
    }
}

extern "C" void kernel_launch(void* const* d_in, const int* in_sizes, int n_in,
                              void* d_out, int out_size, void* d_ws, size_t ws_size,
                              hipStream_t stream) {
    const float* x    = (const float*)d_in[0];
    const float* w    = (const float*)d_in[1];
    const float* bias = (const float*)d_in[2];
    float* out = (float*)d_out;
    uint16_t* wt = (uint16_t*)d_ws;   // needs 147456 B of workspace

    prep_weights<<<288, 256, 0, stream>>>(w, wt);
    conv_mfma<<<NBLK, 256, 0, stream>>>(x, wt, bias, out);
}

// Round 2
// 174.404 us; speedup vs baseline: 1.2070x; 1.2070x over previous
//
#include <hip/hip_runtime.h>
#include <stdint.h>

// 3x3 conv s1 p1, NCHW fp32, 64->128 ch, 16x112x112.
// Implicit GEMM on bf16 MFMA with NHWC bf16 x-repack in d_ws:
//   prep:  x (NCHW fp32) -> x_t[(n*12544+p)*64+ic] bf16 ; w -> Wt[tap][oc][ic] bf16 ; 128B zero block
//   conv:  per block 128oc x 128px tile; 9 taps, per tap stage As(16KB)+Xs(16KB) via
//          global_load_lds width=16 (XOR-swizzled chunks), 32 MFMA (16x16x32 bf16).
// Boundary pixels: per-lane global address redirected to the zero block (no LDS patching).

#define HW     112
#define PIX    12544
#define ICN    64
#define OCN    128
#define TILEP  128
#define PTILES 98
#define NBLK   1568
#define NIMG   16

#define XT_BYTES   (NIMG * PIX * ICN * 2)          // 25,690,112
#define WT_OFF     XT_BYTES
#define WT_BYTES   (9 * OCN * ICN * 2)             // 147,456
#define ZG_OFF     (WT_OFF + WT_BYTES)             // 128B zero block
#define XBLK       (NIMG * (PIX / 64))             // 3136 transpose blocks
#define WBLK       72                              // 72 * 1024 = 73728 weight elems

typedef __attribute__((ext_vector_type(8))) __bf16 bf16x8;
typedef __attribute__((ext_vector_type(4))) float  f32x4;

__device__ __forceinline__ uint32_t rne_lo(float f) {
    uint32_t u = __builtin_bit_cast(uint32_t, f);
    return (u + 0x7fffu + ((u >> 16) & 1u)) >> 16;
}
__device__ __forceinline__ uint32_t pk2(float a, float b) {
    uint32_t ub = __builtin_bit_cast(uint32_t, b);
    ub = (ub + 0x7fffu + ((ub >> 16) & 1u)) & 0xffff0000u;
    return rne_lo(a) | ub;
}

__device__ __forceinline__ void load_lds16(const void* g, void* l) {
    __builtin_amdgcn_global_load_lds(
        (const __attribute__((address_space(1))) uint32_t*)g,
        (__attribute__((address_space(3))) uint32_t*)l, 16, 0, 0);
}

// ---------------- prep: x transpose+cvt, weight transpose+cvt, zero block ----------------
__global__ void __launch_bounds__(256)
prep(const float* __restrict__ x, const float* __restrict__ w, uint8_t* __restrict__ ws) {
    const int b = blockIdx.x;
    const int t = threadIdx.x;
    uint16_t* xt = (uint16_t*)ws;
    uint16_t* wt = (uint16_t*)(ws + WT_OFF);

    if (b < XBLK) {
        // 64 pixels per block; thread: pixel = t>>2, ic chunk q = t&3 (16 ic each)
        const int n  = b / (PIX / 64);
        const int p0 = (b - n * (PIX / 64)) * 64;
        const int px = t >> 2;
        const int q  = t & 3;
        const float* src = x + ((size_t)n * ICN + q * 16) * PIX + p0 + px;
        float v[16];
#pragma unroll
        for (int i = 0; i < 16; ++i) v[i] = src[(size_t)i * PIX];
        uint4 u0 = make_uint4(pk2(v[0], v[1]),  pk2(v[2], v[3]),
                              pk2(v[4], v[5]),  pk2(v[6], v[7]));
        uint4 u1 = make_uint4(pk2(v[8], v[9]),  pk2(v[10], v[11]),
                              pk2(v[12], v[13]), pk2(v[14], v[15]));
        char* dst = (char*)xt + ((size_t)(n * PIX + p0 + px)) * 128 + q * 32;
        *(uint4*)dst        = u0;
        *(uint4*)(dst + 16) = u1;
    } else {
        const int wb = b - XBLK;
#pragma unroll
        for (int k = 0; k < 4; ++k) {
            int wi = wb * 1024 + k * 256 + t;          // [0, 73728)
            int r  = wi >> 13;
            int oc = (wi >> 6) & 127;
            int ic = wi & 63;
            wt[wi] = (uint16_t)rne_lo(w[oc * 576 + ic * 9 + r]);
        }
        if (wb == 0 && t < 8) ((uint4*)(ws + ZG_OFF))[t] = make_uint4(0, 0, 0, 0);
    }
}

// ---------------- main conv ----------------
__global__ void __launch_bounds__(256)
conv_mfma(const uint8_t* __restrict__ ws, const float* __restrict__ bias,
          float* __restrict__ out) {
    __shared__ uint16_t As[8192];   // [oc 0..127][ic chunk swizzled] 128B rows
    __shared__ uint16_t Xs[8192];   // [px 0..127][ic chunk swizzled] 128B rows

    const char* xt = (const char*)ws;
    const char* wt = (const char*)(ws + WT_OFF);
    const char* zg = (const char*)(ws + ZG_OFF);

    const int t = threadIdx.x;
    const int b = blockIdx.x;
    const int n_img = b / PTILES;
    const int p0 = (b - n_img * PTILES) * TILEP;

    const int lane = t & 63;
    const int wave = t >> 6;
    const int lr = lane & 15;
    const int lq = lane >> 4;
    const int oc_base = (wave & 1) * 64;
    const int px_base = (wave >> 1) * 64;

    // ---- staging geometry: slot = r2*256 + t; row = r2*32 + (t>>3); cpos = t&7
    const int rowB = t >> 3;                   // 0..31
    const int cswz = (t & 7) ^ (rowB & 7);     // row&7 == rowB&7 (r2*32 = 0 mod 8)
    int sh[4], sw[4];
    const char* xaddr[4];
#pragma unroll
    for (int r2 = 0; r2 < 4; ++r2) {
        int row = r2 * 32 + rowB;
        int p = p0 + row;
        int hh = p / HW;
        sh[r2] = hh;
        sw[r2] = p - hh * HW;
        xaddr[r2] = xt + ((size_t)(n_img * PIX + p)) * 128 + cswz * 16;
    }
    const char* waddr0 = wt + rowB * 128 + cswz * 16;
    const char* zaddr  = zg + (t & 7) * 16;

    f32x4 acc[4][4];
    {
        f32x4 z = {0.f, 0.f, 0.f, 0.f};
#pragma unroll
        for (int i = 0; i < 4; ++i)
#pragma unroll
            for (int j = 0; j < 4; ++j) acc[i][j] = z;
    }

#pragma unroll
    for (int tap = 0; tap < 9; ++tap) {
        const int dy = tap / 3 - 1;
        const int dx = tap - (tap / 3) * 3 - 1;
        const int toff = (dy * HW + dx) * 128;

        __syncthreads();   // all waves done reading previous tap's LDS

        // weights -> As
#pragma unroll
        for (int r2 = 0; r2 < 4; ++r2)
            load_lds16(waddr0 + tap * 16384 + r2 * 4096,
                       (char*)As + r2 * 4096 + wave * 1024);
        // x -> Xs (invalid rows redirected to zero block)
#pragma unroll
        for (int r2 = 0; r2 < 4; ++r2) {
            int hh = sh[r2] + dy;
            int wwp = sw[r2] + dx;
            bool ok = ((unsigned)hh < HW) & ((unsigned)wwp < HW);
            const char* gp = ok ? (xaddr[r2] + toff) : zaddr;
            load_lds16(gp, (char*)Xs + r2 * 4096 + wave * 1024);
        }

        __syncthreads();   // DMA drained (compiler emits vmcnt(0) before barrier)

#pragma unroll
        for (int kh = 0; kh < 2; ++kh) {
            bf16x8 a_frag[4], b_frag[4];
            const int cc = kh * 4 + lq;
#pragma unroll
            for (int mi = 0; mi < 4; ++mi) {
                int R = oc_base + mi * 16 + lr;
                a_frag[mi] = *(const bf16x8*)((const char*)As + R * 128 + ((cc ^ (R & 7)) * 16));
            }
#pragma unroll
            for (int ni = 0; ni < 4; ++ni) {
                int R = px_base + ni * 16 + lr;
                b_frag[ni] = *(const bf16x8*)((const char*)Xs + R * 128 + ((cc ^ (R & 7)) * 16));
            }
#pragma unroll
            for (int mi = 0; mi < 4; ++mi)
#pragma unroll
                for (int ni = 0; ni < 4; ++ni)
                    acc[mi][ni] = __builtin_amdgcn_mfma_f32_16x16x32_bf16(
                        a_frag[mi], b_frag[ni], acc[mi][ni], 0, 0, 0);
        }
    }

    // ---- epilogue: D col = lane&15 -> pixel, row = lq*4+reg -> oc (validated R1)
#pragma unroll
    for (int mi = 0; mi < 4; ++mi) {
#pragma unroll
        for (int rg = 0; rg < 4; ++rg) {
            const int oc = oc_base + mi * 16 + lq * 4 + rg;
            const float bb = bias[oc];
            float* orow = out + ((size_t)n_img * OCN + oc) * PIX + p0 + px_base + lr;
#pragma unroll
            for (int ni = 0; ni < 4; ++ni)
                orow[ni * 16] = acc[mi][ni][rg] + bb;
        }
    }
}

extern "C" void kernel_launch(void* const* d_in, const int* in_sizes, int n_in,
                              void* d_out, int out_size, void* d_ws, size_t ws_size,
                              hipStream_t stream) {
    const float* x    = (const float*)d_in[0];
    const float* w    = (const float*)d_in[1];
    const float* bias = (const float*)d_in[2];
    float* out = (float*)d_out;
    uint8_t* ws = (uint8_t*)d_ws;   // needs ZG_OFF + 128 = 25,837,696 bytes

    prep<<<XBLK + WBLK, 256, 0, stream>>>(x, w, ws);
    conv_mfma<<<NBLK, 256, 0, stream>>>(ws, bias, out);
}